// Round 3
// baseline (72.777 us; speedup 1.0000x reference)
//
#include <hip/hip_runtime.h>
#include <hip/hip_bf16.h>

typedef __attribute__((ext_vector_type(8))) short bf16x8;
typedef __attribute__((ext_vector_type(4))) float f32x4;
typedef unsigned short u16;

static __device__ __forceinline__ u16 f2bf(float f) {
  unsigned u = __builtin_bit_cast(unsigned, f);
  return (u16)((u + 0x7fffu + ((u >> 16) & 1u)) >> 16);
}

// ================= K1: weights -> Apre (256x1024 bf16), Bmat (1024x256 bf16) ==========
// Blocks 0..63 (type A): block b owns Apre rows p = 4b..4b+3  (r1 = b>>2, j3 = 4(b&3)+pd)
//   T1 slice [j1][i1][i0] (512):   T1 = sum_r0 W1[j1,i1*16+r0] * W0[r0*16+r1, i0]
//   V1 slice [i2][j1][pd][i3](2048): V1 = sum_j2 W3[j3base+pd, i3*16+j2] * W2[j2, i2*16+j1]
//   Apre[p][i0*256+i1*32+i2*4+i3] = sum_j1 V1 * T1
// Blocks 64..127 (type B): c = b-64 owns Bmat rows o = 16c..16c+15
//   (kh = c>>4, j5h = (c>>1)&7, j6h = 4(c&1)+j6hd, od = j6hd*4+m7)
//   U1 slice [j5l][j3] (256):      U1 = sum_kl W5[j5h*16+j5l, kl] * W4[kh*16+kl, j3]
//   V2 slice [m7][r1][j6hd][j5l] (4096): V2 = sum_d W7[m7, r1*16+d] * W6[j6h*16+d, j5l]
//   Bmat[o][r1*16+j3] = sum_j5l V2 * U1
__global__ __launch_bounds__(256) void trl_w(
    const float* __restrict__ W0, const float* __restrict__ W1,
    const float* __restrict__ W2, const float* __restrict__ W3,
    const float* __restrict__ W4, const float* __restrict__ W5,
    const float* __restrict__ W6, const float* __restrict__ W7,
    u16* __restrict__ Apre, u16* __restrict__ Bmat) {
  __shared__ float S1[512];
  __shared__ float S2[4096];
  const int tid = threadIdx.x;
  const int b = blockIdx.x;
  if (b < 64) {
    const int r1 = b >> 2;
    const int j3base = (b & 3) << 2;
#pragma unroll
    for (int e0 = 0; e0 < 512; e0 += 256) {
      const int e = e0 + tid;
      const int i0 = e & 3, i1 = (e >> 2) & 7, j1 = e >> 5;
      float s = 0.f;
#pragma unroll
      for (int r0 = 0; r0 < 16; ++r0)
        s += W1[j1 * 128 + i1 * 16 + r0] * W0[(r0 * 16 + r1) * 4 + i0];
      S1[e] = s;  // [j1*32 + i1*4 + i0]
    }
#pragma unroll
    for (int e0 = 0; e0 < 2048; e0 += 256) {
      const int e = e0 + tid;
      const int i3 = e & 3, pd = (e >> 2) & 3, j1 = (e >> 4) & 15, i2 = e >> 8;
      float s = 0.f;
#pragma unroll
      for (int j2 = 0; j2 < 16; ++j2)
        s += W3[(j3base + pd) * 64 + i3 * 16 + j2] * W2[j2 * 128 + i2 * 16 + j1];
      S2[e] = s;  // [i2*256 + j1*16 + pd*4 + i3]
    }
    __syncthreads();
    const int i0 = tid & 3, i1 = (tid >> 2) & 7, i2 = tid >> 5;
#pragma unroll
    for (int pd = 0; pd < 4; ++pd) {
      float a0 = 0.f, a1 = 0.f, a2 = 0.f, a3 = 0.f;
#pragma unroll
      for (int j1 = 0; j1 < 16; ++j1) {
        const float t = S1[j1 * 32 + i1 * 4 + i0];
        const float4 v = *(const float4*)&S2[i2 * 256 + j1 * 16 + pd * 4];
        a0 += t * v.x; a1 += t * v.y; a2 += t * v.z; a3 += t * v.w;
      }
      ushort4 o4;
      o4.x = f2bf(a0); o4.y = f2bf(a1); o4.z = f2bf(a2); o4.w = f2bf(a3);
      *(ushort4*)&Apre[(size_t)(4 * b + pd) * 1024 + i0 * 256 + i1 * 32 + i2 * 4] = o4;
    }
  } else {
    const int c = b - 64;
    const int kh = c >> 4, j5h = (c >> 1) & 7, j6hbase = (c & 1) << 2;
    {
      const int j5l = tid >> 4, j3 = tid & 15;
      float s = 0.f;
#pragma unroll
      for (int kl = 0; kl < 16; ++kl)
        s += W5[(j5h * 16 + j5l) * 16 + kl] * W4[(kh * 16 + kl) * 16 + j3];
      S1[tid] = s;  // [j5l*16 + j3]
    }
#pragma unroll
    for (int e0 = 0; e0 < 4096; e0 += 256) {
      const int e = e0 + tid;
      const int j5l = e & 15, j6hd = (e >> 4) & 3, r1 = (e >> 6) & 15, m7 = e >> 10;
      float s = 0.f;
#pragma unroll
      for (int d = 0; d < 16; ++d)
        s += W7[m7 * 256 + r1 * 16 + d] * W6[((j6hbase + j6hd) * 16 + d) * 16 + j5l];
      S2[e] = s;  // [((m7*16+r1)*4 + j6hd)*16 + j5l]
    }
    __syncthreads();
    const int r1 = (tid >> 2) & 15, j3q = tid & 3;
#pragma unroll
    for (int qq = 0; qq < 4; ++qq) {
      const int od = qq * 4 + (tid >> 6);
      const int m7 = od & 3, j6hd = od >> 2;
      float a0 = 0.f, a1 = 0.f, a2 = 0.f, a3 = 0.f;
#pragma unroll
      for (int j5l = 0; j5l < 16; ++j5l) {
        const float w = S2[((m7 * 16 + r1) * 4 + j6hd) * 16 + j5l];
        const float4 u = *(const float4*)&S1[j5l * 16 + j3q * 4];
        a0 += w * u.x; a1 += w * u.y; a2 += w * u.z; a3 += w * u.w;
      }
      ushort4 o4;
      o4.x = f2bf(a0); o4.y = f2bf(a1); o4.z = f2bf(a2); o4.w = f2bf(a3);
      *(ushort4*)&Bmat[(size_t)(16 * c + od) * 256 + r1 * 16 + j3q * 4] = o4;
    }
  }
}

// ================= K2: fused GEMM per 16-row m-slab (64 blocks x 4 waves) ==============
// Phase 1: Cb_slab(16x256) = bf16(x_slab 16x1024) @ Apre^T  -> swizzled LDS (bf16)
// Phase 2: out_slab(16x1024) = Cb_slab @ Bmat^T + bias
__global__ __launch_bounds__(256) void trl_g(const float* __restrict__ x,
                                             const u16* __restrict__ Apre,
                                             const u16* __restrict__ Bmat,
                                             const float* __restrict__ bias,
                                             float* __restrict__ out) {
  __shared__ u16 Cbs[16 * 256];  // addr(row,col) = row*256 + (((col>>3)^(row&7))<<3 | (col&7))
  const int tid = threadIdx.x;
  const int wave = tid >> 6, lane = tid & 63;
  const int l15 = lane & 15, l4 = lane >> 4;
  const int m0 = blockIdx.x * 16;

  // ---- phase 1: wave w covers Cb cols [64w, 64w+64) ----
  f32x4 acc1[4] = {};
  {
    const float* xrow = x + (size_t)(m0 + l15) * 1024;
#pragma unroll 4
    for (int kb = 0; kb < 32; ++kb) {
      const int k = kb * 32 + l4 * 8;
      const float4 f0 = *(const float4*)&xrow[k];
      const float4 f1 = *(const float4*)&xrow[k + 4];
      bf16x8 af;
      af[0] = (short)f2bf(f0.x); af[1] = (short)f2bf(f0.y);
      af[2] = (short)f2bf(f0.z); af[3] = (short)f2bf(f0.w);
      af[4] = (short)f2bf(f1.x); af[5] = (short)f2bf(f1.y);
      af[6] = (short)f2bf(f1.z); af[7] = (short)f2bf(f1.w);
#pragma unroll
      for (int nt = 0; nt < 4; ++nt) {
        const bf16x8 bf = *(const bf16x8*)&Apre[(size_t)(wave * 64 + nt * 16 + l15) * 1024 + k];
        acc1[nt] = __builtin_amdgcn_mfma_f32_16x16x32_bf16(af, bf, acc1[nt], 0, 0, 0);
      }
    }
  }
#pragma unroll
  for (int nt = 0; nt < 4; ++nt) {
    const int col = wave * 64 + nt * 16 + l15;
#pragma unroll
    for (int r = 0; r < 4; ++r) {
      const int row = l4 * 4 + r;
      Cbs[row * 256 + ((((col >> 3) ^ (row & 7)) << 3) | (col & 7))] = f2bf(acc1[nt][r]);
    }
  }
  __syncthreads();

  // ---- phase 2: wave w covers out cols [256w, 256w+256) ----
  f32x4 acc2[16] = {};
#pragma unroll 2
  for (int kb = 0; kb < 8; ++kb) {
    const int g = kb * 4 + l4;
    const bf16x8 af = *(const bf16x8*)&Cbs[l15 * 256 + ((g ^ (l15 & 7)) << 3)];
#pragma unroll
    for (int nt = 0; nt < 16; ++nt) {
      const bf16x8 bf =
          *(const bf16x8*)&Bmat[(size_t)(wave * 256 + nt * 16 + l15) * 256 + kb * 32 + l4 * 8];
      acc2[nt] = __builtin_amdgcn_mfma_f32_16x16x32_bf16(af, bf, acc2[nt], 0, 0, 0);
    }
  }
#pragma unroll
  for (int nt = 0; nt < 16; ++nt) {
    const int col = wave * 256 + nt * 16 + l15;
    const float bv = bias[col];
#pragma unroll
    for (int r = 0; r < 4; ++r)
      out[(size_t)(m0 + l4 * 4 + r) * 1024 + col] = acc2[nt][r] + bv;
  }
}

extern "C" void kernel_launch(void* const* d_in, const int* in_sizes, int n_in,
                              void* d_out, int out_size, void* d_ws, size_t ws_size,
                              hipStream_t stream) {
  const float* x  = (const float*)d_in[0];
  const float* W0 = (const float*)d_in[1];
  const float* W1 = (const float*)d_in[2];
  const float* W2 = (const float*)d_in[3];
  const float* W3 = (const float*)d_in[4];
  const float* W4 = (const float*)d_in[5];
  const float* W5 = (const float*)d_in[6];
  const float* W6 = (const float*)d_in[7];
  const float* W7 = (const float*)d_in[8];
  const float* bias = (const float*)d_in[9];

  char* ws = (char*)d_ws;
  u16* Apre = (u16*)(ws);                  // 512 KB (256x1024 bf16)
  u16* Bmat = (u16*)(ws + (512 << 10));    // 512 KB (1024x256 bf16)
  float* outp = (float*)d_out;

  trl_w<<<128, 256, 0, stream>>>(W0, W1, W2, W3, W4, W5, W6, W7, Apre, Bmat);
  trl_g<<<64, 256, 0, stream>>>(x, Apre, Bmat, bias, outp);
}